// Round 7
// baseline (339.447 us; speedup 1.0000x reference)
//
#include <hip/hip_runtime.h>

#define DIM   256
#define NE    8192
#define NTOK  16384

// d_out flat offsets (floats)
#define OFF_Q    0
#define OFF_DIFF 4194304
#define OFF_IND  4194305
#define OFF_OH   4210689
#define OFF_ES   4218881

#define NCAND 256     // keys per token: 4 nbg x 2 wn x 16 col x top-2

typedef __attribute__((ext_vector_type(8))) short short8;
typedef __attribute__((ext_vector_type(4))) float floatx4;

__device__ inline unsigned umin2(unsigned a, unsigned b) { return a < b ? a : b; }
__device__ inline unsigned umax2(unsigned a, unsigned b) { return a > b ? a : b; }

__device__ inline void gl_lds16(const void* g, void* l) {
    __builtin_amdgcn_global_load_lds(
        (const __attribute__((address_space(1))) unsigned int*)g,
        (__attribute__((address_space(3))) unsigned int*)l, 16, 0, 0);
}

__device__ inline unsigned short b16rn(float f) {
    unsigned u = __float_as_uint(f);
    unsigned r = (u + 0x7fffu + ((u >> 16) & 1u)) >> 16;
    return (unsigned short)r;
}

// ---------------------------------------------------------------------------
// Xbf[m][d] = bf16(x[m][d])  (row-major; A-fragments read directly from this)
__global__ void convert_x_kernel(const float* __restrict__ x,
                                 unsigned short* __restrict__ Xbf) {
    int i = blockIdx.x * 256 + threadIdx.x;   // float4 index
    float4 v = ((const float4*)x)[i];
    ushort4 h;
    h.x = b16rn(v.x); h.y = b16rn(v.y); h.z = b16rn(v.z); h.w = b16rn(v.w);
    ((ushort4*)Xbf)[i] = h;
}

// ---------------------------------------------------------------------------
// convert_e: embed -> (a) EbfT tiled bf16(-512*e) in the EXACT order the
// screen's gl_lds staging + fragment reads want: [tile128][kb8][quad4][n128][8],
// (b) embedT fp32 [n][d] for rescore/gather, (c) e2 / es2 per code.
__global__ void convert_e_kernel(const float* __restrict__ embed,
                                 unsigned short* __restrict__ EbfT,
                                 float* __restrict__ embedT,
                                 float* __restrict__ e2,
                                 float* __restrict__ es2) {
    __shared__ __align__(16) float t2[32][DIM + 4];
    __shared__ float red[32][8];
    int c0 = blockIdx.x * 32;
    int tid = threadIdx.x;
    for (int t = 0; t < 32; ++t) {
        int i = t * 256 + tid;
        int d = i >> 5, c = i & 31;
        t2[c][d] = embed[(size_t)d * NE + c0 + c];
    }
    __syncthreads();
    for (int t = 0; t < 8; ++t) {
        int i = t * 256 + tid;          // 0..2047 float4 units
        int c = i >> 6, dq = i & 63;    // code-local, k-quad (k = 4*dq)
        float4 v = *(const float4*)&t2[c][dq * 4];
        *(float4*)&embedT[(size_t)(c0 + c) * DIM + dq * 4] = v;
        ushort4 h;
        h.x = b16rn(-512.0f * v.x); h.y = b16rn(-512.0f * v.y);
        h.z = b16rn(-512.0f * v.z); h.w = b16rn(-512.0f * v.w);
        int C = c0 + c;
        int nb = C >> 7, n = C & 127;
        size_t off = (size_t)nb * 32768 + (size_t)(dq >> 3) * 4096 +
                     (size_t)((dq >> 1) & 3) * 1024 + (size_t)n * 8 + (dq & 1) * 4;
        *(ushort4*)&EbfT[off] = h;
    }
    // e2: 8 threads per code, 32 d each
    {
        int c = tid >> 3, seg = tid & 7;
        float s = 0.f;
        for (int d = seg * 32; d < seg * 32 + 32; ++d)
            s = fmaf(t2[c][d], t2[c][d], s);
        red[c][seg] = s;
    }
    __syncthreads();
    if (tid < 32) {
        float s = 0.f;
        for (int j = 0; j < 8; ++j) s += red[tid][j];
        e2[c0 + tid] = s;
        es2[c0 + tid] = 256.0f * (512.0f + s);
    }
}

// ---------------------------------------------------------------------------
// Screening GEMM (unchanged from round 6): A-fragments register-resident,
// B staged 64 KB per barrier pair. Per-lane running top-2 packed keys.
__global__ __launch_bounds__(256, 2) void dist_screen_kernel(
    const unsigned short* __restrict__ Xbf,
    const unsigned short* __restrict__ EbfT,
    const float* __restrict__ es2,
    unsigned int* __restrict__ cand) {
    __shared__ __align__(16) unsigned short Bs[32768];   // 64 KB [kb][quad][n][8]

    const int tid  = threadIdx.x;
    const int lane = tid & 63;
    const int wid  = tid >> 6;
    const int wm   = wid >> 1, wn = wid & 1;
    const int col  = lane & 15, quad = lane >> 4;
    const int nbg  = blockIdx.x;           // 0..3
    const int m0   = blockIdx.y * 128;

    short8 af[4][8];
#pragma unroll
    for (int mi = 0; mi < 4; ++mi) {
        const unsigned short* base =
            Xbf + (size_t)(m0 + wm * 64 + mi * 16 + col) * DIM + quad * 8;
#pragma unroll
        for (int kb = 0; kb < 8; ++kb)
            af[mi][kb] = *(const short8*)(base + kb * 32);
    }

    unsigned b1[16], b2[16];
#pragma unroll
    for (int i = 0; i < 16; ++i) { b1[i] = 0xFFFFFFFFu; b2[i] = 0xFFFFFFFFu; }

    const unsigned short* gsrc = EbfT + (size_t)nbg * 16 * 32768 + tid * 8;
    char* ldst = (char*)Bs + tid * 16;

    for (int nt = 0; nt < 16; ++nt) {
        const int n0 = nbg * 2048 + nt * 128;
        __syncthreads();
#pragma unroll
        for (int i = 0; i < 16; ++i)
            gl_lds16(gsrc + (size_t)nt * 32768 + i * 2048, ldst + i * 4096);
        __syncthreads();

        float e_l[4];
#pragma unroll
        for (int ni = 0; ni < 4; ++ni)
            e_l[ni] = es2[n0 + wn * 64 + ni * 16 + col];

#pragma unroll
        for (int nh = 0; nh < 2; ++nh) {
            floatx4 acc[4][2];
#pragma unroll
            for (int mi = 0; mi < 4; ++mi) {
                acc[mi][0] = (floatx4)0.f; acc[mi][1] = (floatx4)0.f;
            }
            const int n_a = wn * 64 + (nh * 2 + 0) * 16 + col;
            const int n_b = wn * 64 + (nh * 2 + 1) * 16 + col;
#pragma unroll
            for (int kb = 0; kb < 8; ++kb) {
                short8 bf0 = *(const short8*)&Bs[kb * 4096 + quad * 1024 + n_a * 8];
                short8 bf1 = *(const short8*)&Bs[kb * 4096 + quad * 1024 + n_b * 8];
#pragma unroll
                for (int mi = 0; mi < 4; ++mi) {
                    acc[mi][0] = __builtin_amdgcn_mfma_f32_16x16x32_bf16(
                        af[mi][kb], bf0, acc[mi][0], 0, 0, 0);
                    acc[mi][1] = __builtin_amdgcn_mfma_f32_16x16x32_bf16(
                        af[mi][kb], bf1, acc[mi][1], 0, 0, 0);
                }
            }
#pragma unroll
            for (int nj = 0; nj < 2; ++nj) {
                int ni = nh * 2 + nj;
                unsigned idxc = (unsigned)(n0 + wn * 64 + ni * 16 + col);
                float e = e_l[ni];
#pragma unroll
                for (int mi = 0; mi < 4; ++mi)
#pragma unroll
                    for (int r = 0; r < 4; ++r) {
                        float d = e + acc[mi][nj][r];
                        unsigned key = ((unsigned)d << 13) + idxc;
                        int s = mi * 4 + r;
                        unsigned lo = umin2(key, b1[s]);
                        unsigned hi = umax2(key, b1[s]);
                        b1[s] = lo;
                        b2[s] = umin2(hi, b2[s]);
                    }
            }
        }
    }

#pragma unroll
    for (int mi = 0; mi < 4; ++mi)
#pragma unroll
        for (int r = 0; r < 4; ++r) {
            int token = m0 + wm * 64 + mi * 16 + quad * 4 + r;
            uint2 v; v.x = b1[mi * 4 + r]; v.y = b2[mi * 4 + r];
            *(uint2*)&cand[(size_t)token * NCAND + nbg * 64 + wn * 32 + col * 2] = v;
        }
}

// ---------------------------------------------------------------------------
// Exact fp32 rescore + quantize write + histogram + diff. NO embed_sum
// atomics here (that write-through traffic was 58 MB of HBM in round 6).
__global__ __launch_bounds__(256) void finalize_kernel(
    const float* __restrict__ x, const float* __restrict__ embedT,
    const float* __restrict__ e2,
    const unsigned int* __restrict__ cand,
    int* __restrict__ ind, float* __restrict__ out) {
    __shared__ float partial[4];
    int tid = threadIdx.x, w = tid >> 6, lane = tid & 63;
    int token = blockIdx.x * 4 + w;

    float4 xv = *(const float4*)&x[(size_t)token * DIM + lane * 4];
    float x2 = xv.x * xv.x + xv.y * xv.y + xv.z * xv.z + xv.w * xv.w;
    uint4 c = *(const uint4*)&cand[(size_t)token * NCAND + lane * 4];
    unsigned g = umin2(umin2(c.x, c.y), umin2(c.z, c.w));
#pragma unroll
    for (int m = 1; m < 64; m <<= 1) {
        x2 += __shfl_xor(x2, m);
        g = umin2(g, (unsigned)__shfl_xor((int)g, m));
    }
    const unsigned thr = g + (384u << 13);   // margin 1.5 in true-dist units

    float bd = 3.4e38f; int bk = 0x7fffffff;
    float4 bq = make_float4(0.f, 0.f, 0.f, 0.f);
    unsigned ca[4] = {c.x, c.y, c.z, c.w};
#pragma unroll
    for (int s = 0; s < 4; ++s) {
        unsigned long long mask = __ballot(ca[s] <= thr);
        while (mask) {
            int l = __ffsll(mask) - 1;
            mask &= mask - 1;
            int k = __shfl((int)ca[s], l) & 8191;
            float4 ev = *(const float4*)&embedT[(size_t)k * DIM + lane * 4];
            float p = xv.x * ev.x;
            p = fmaf(xv.y, ev.y, p);
            p = fmaf(xv.z, ev.z, p);
            p = fmaf(xv.w, ev.w, p);
#pragma unroll
            for (int m = 1; m < 64; m <<= 1) p += __shfl_xor(p, m);
            float d = e2[k] - 2.0f * p;
            if (d < bd || (d == bd && k < bk)) { bd = d; bk = k; bq = ev; }
        }
    }
    *(float4*)&out[OFF_Q + (size_t)token * DIM + lane * 4] = bq;
    if (lane == 0) {
        ind[token] = bk;
        out[OFF_IND + token] = (float)bk;
        atomicAdd(&out[OFF_OH + bk], 1.0f);
        partial[w] = x2 + bd;
    }
    __syncthreads();
    if (tid == 0)
        atomicAdd(&out[OFF_DIFF],
                  (partial[0] + partial[1] + partial[2] + partial[3]) *
                  (1.0f / 4194304.0f));
}

// ---------------------------------------------------------------------------
// Exclusive prefix sum of the 8192 OH counts -> start[], cur[] (one block).
__global__ void scan_kernel(const float* __restrict__ out,
                            int* __restrict__ start, int* __restrict__ cur) {
    __shared__ int ps[256];
    int tid = threadIdx.x;
    int base = tid * 32;
    int loc[32];
    int s = 0;
#pragma unroll
    for (int j = 0; j < 32; ++j) {
        int c = (int)(out[OFF_OH + base + j] + 0.5f);
        loc[j] = s; s += c;
    }
    ps[tid] = s;
    __syncthreads();
    for (int d = 1; d < 256; d <<= 1) {
        int v = (tid >= d) ? ps[tid - d] : 0;
        __syncthreads();
        ps[tid] += v;
        __syncthreads();
    }
    int ex = ps[tid] - s;   // exclusive prefix of this thread's chunk
#pragma unroll
    for (int j = 0; j < 32; ++j) {
        int o = ex + loc[j];
        start[base + j] = o;
        cur[base + j] = o;
    }
}

// ---------------------------------------------------------------------------
// Bucket tokens by code: list[start[k] + slot] = token.  16K atomics total.
__global__ void scatter_kernel(const int* __restrict__ ind,
                               int* __restrict__ cur, int* __restrict__ list) {
    int t = blockIdx.x * 256 + threadIdx.x;
    int k = ind[t];
    int pos = atomicAdd(&cur[k], 1);
    list[pos] = t;
}

// ---------------------------------------------------------------------------
// embed_sum: wave-per-code segment sum of x rows, LDS transpose [d][33]
// (2-way bank aliasing both phases = free), direct transposed write to out.
__global__ __launch_bounds__(256) void sum_es_kernel(
    const float* __restrict__ x, const float* __restrict__ out_oh,
    const int* __restrict__ start, const int* __restrict__ list,
    float* __restrict__ out) {
    __shared__ float t2[DIM][33];
    int tid = threadIdx.x, w = tid >> 6, lane = tid & 63;
    int k0 = blockIdx.x * 32;
    for (int j = 0; j < 8; ++j) {
        int c = w * 8 + j;          // code slot 0..31
        int k = k0 + c;
        int s = start[k];
        int cnt = (int)(out_oh[OFF_OH + k] + 0.5f);
        float4 a = make_float4(0.f, 0.f, 0.f, 0.f);
        for (int i = 0; i < cnt; ++i) {
            int t = list[s + i];
            float4 xv = *(const float4*)&x[(size_t)t * DIM + lane * 4];
            a.x += xv.x; a.y += xv.y; a.z += xv.z; a.w += xv.w;
        }
        t2[lane * 4 + 0][c] = a.x;
        t2[lane * 4 + 1][c] = a.y;
        t2[lane * 4 + 2][c] = a.z;
        t2[lane * 4 + 3][c] = a.w;
    }
    __syncthreads();
    for (int t = 0; t < 32; ++t) {
        int i = t * 256 + tid;      // 8192 cells: d = i>>5, c = i&31
        int d = i >> 5, c = i & 31;
        out[OFF_ES + (size_t)d * NE + k0 + c] = t2[d][c];
    }
}

// ===========================================================================
extern "C" void kernel_launch(void* const* d_in, const int* in_sizes, int n_in,
                              void* d_out, int out_size, void* d_ws, size_t ws_size,
                              hipStream_t stream) {
    const float* x     = (const float*)d_in[0];
    const float* embed = (const float*)d_in[1];
    float* out = (float*)d_out;

    // ws layout (~38 MB)
    char* p = (char*)d_ws;
    unsigned short* Xbf  = (unsigned short*)p;  p += (size_t)NTOK * DIM * 2;    // 8.4 MB
    unsigned short* EbfT = (unsigned short*)p;  p += (size_t)NE * DIM * 2;      // 4.2 MB (tiled)
    float* embedT = (float*)p;                  p += (size_t)NE * DIM * 4;      // 8.4 MB
    float* e2     = (float*)p;                  p += (size_t)NE * 4;
    float* es2    = (float*)p;                  p += (size_t)NE * 4;
    unsigned int* cand = (unsigned int*)p;      p += (size_t)NTOK * NCAND * 4;  // 16.8 MB
    int*   ind    = (int*)p;                    p += (size_t)NTOK * 4;
    int*   start  = (int*)p;                    p += (size_t)NE * 4;
    int*   cur    = (int*)p;                    p += (size_t)NE * 4;
    int*   list   = (int*)p;                    p += (size_t)NTOK * 4;

    // zero DIFF/IND/OH header (Q and ES are fully overwritten)
    hipMemsetAsync((char*)d_out + (size_t)OFF_DIFF * 4, 0,
                   ((size_t)(OFF_ES - OFF_DIFF)) * 4, stream);

    convert_x_kernel<<<(NTOK * DIM / 4) / 256, 256, 0, stream>>>(x, Xbf);
    convert_e_kernel<<<NE / 32, 256, 0, stream>>>(embed, EbfT, embedT, e2, es2);
    dist_screen_kernel<<<dim3(4, NTOK / 128), 256, 0, stream>>>(
        Xbf, EbfT, es2, cand);
    finalize_kernel<<<NTOK / 4, 256, 0, stream>>>(
        x, embedT, e2, cand, ind, out);
    scan_kernel<<<1, 256, 0, stream>>>(out, start, cur);
    scatter_kernel<<<NTOK / 256, 256, 0, stream>>>(ind, cur, list);
    sum_es_kernel<<<NE / 32, 256, 0, stream>>>(x, out, start, list, out);
}

// Round 8
// 327.106 us; speedup vs baseline: 1.0377x; 1.0377x over previous
//
#include <hip/hip_runtime.h>

#define DIM   256
#define NE    8192
#define NTOK  16384

// d_out flat offsets (floats)
#define OFF_Q    0
#define OFF_DIFF 4194304
#define OFF_IND  4194305
#define OFF_OH   4210689
#define OFF_ES   4218881

#define NCAND 256     // keys per token: 4 nbg x 2 wn x 16 col x top-2

typedef __attribute__((ext_vector_type(8))) short short8;
typedef __attribute__((ext_vector_type(4))) float floatx4;

__device__ inline unsigned umin2(unsigned a, unsigned b) { return a < b ? a : b; }
__device__ inline unsigned umax2(unsigned a, unsigned b) { return a > b ? a : b; }

__device__ inline void gl_lds16(const void* g, void* l) {
    __builtin_amdgcn_global_load_lds(
        (const __attribute__((address_space(1))) unsigned int*)g,
        (__attribute__((address_space(3))) unsigned int*)l, 16, 0, 0);
}

__device__ inline unsigned short b16rn(float f) {
    unsigned u = __float_as_uint(f);
    unsigned r = (u + 0x7fffu + ((u >> 16) & 1u)) >> 16;
    return (unsigned short)r;
}

// ---------------------------------------------------------------------------
// Xbf[m][d] = bf16(x[m][d])  (row-major; A-fragments read directly from this)
__global__ void convert_x_kernel(const float* __restrict__ x,
                                 unsigned short* __restrict__ Xbf) {
    int i = blockIdx.x * 256 + threadIdx.x;   // float4 index
    float4 v = ((const float4*)x)[i];
    ushort4 h;
    h.x = b16rn(v.x); h.y = b16rn(v.y); h.z = b16rn(v.z); h.w = b16rn(v.w);
    ((ushort4*)Xbf)[i] = h;
}

// ---------------------------------------------------------------------------
// convert_e: embed -> (a) EbfT tiled bf16(-512*e) in the EXACT order the
// screen's gl_lds staging + fragment reads want: [tile128][kb8][quad4][n128][8],
// (b) embedT fp32 [n][d] for rescore/gather, (c) e2 / es2 per code.
__global__ void convert_e_kernel(const float* __restrict__ embed,
                                 unsigned short* __restrict__ EbfT,
                                 float* __restrict__ embedT,
                                 float* __restrict__ e2,
                                 float* __restrict__ es2) {
    __shared__ __align__(16) float t2[32][DIM + 4];
    __shared__ float red[32][8];
    int c0 = blockIdx.x * 32;
    int tid = threadIdx.x;
    for (int t = 0; t < 32; ++t) {
        int i = t * 256 + tid;
        int d = i >> 5, c = i & 31;
        t2[c][d] = embed[(size_t)d * NE + c0 + c];
    }
    __syncthreads();
    for (int t = 0; t < 8; ++t) {
        int i = t * 256 + tid;          // 0..2047 float4 units
        int c = i >> 6, dq = i & 63;    // code-local, k-quad (k = 4*dq)
        float4 v = *(const float4*)&t2[c][dq * 4];
        *(float4*)&embedT[(size_t)(c0 + c) * DIM + dq * 4] = v;
        ushort4 h;
        h.x = b16rn(-512.0f * v.x); h.y = b16rn(-512.0f * v.y);
        h.z = b16rn(-512.0f * v.z); h.w = b16rn(-512.0f * v.w);
        int C = c0 + c;
        int nb = C >> 7, n = C & 127;
        size_t off = (size_t)nb * 32768 + (size_t)(dq >> 3) * 4096 +
                     (size_t)((dq >> 1) & 3) * 1024 + (size_t)n * 8 + (dq & 1) * 4;
        *(ushort4*)&EbfT[off] = h;
    }
    // e2: 8 threads per code, 32 d each
    {
        int c = tid >> 3, seg = tid & 7;
        float s = 0.f;
        for (int d = seg * 32; d < seg * 32 + 32; ++d)
            s = fmaf(t2[c][d], t2[c][d], s);
        red[c][seg] = s;
    }
    __syncthreads();
    if (tid < 32) {
        float s = 0.f;
        for (int j = 0; j < 8; ++j) s += red[tid][j];
        e2[c0 + tid] = s;
        es2[c0 + tid] = 256.0f * (512.0f + s);
    }
}

// ---------------------------------------------------------------------------
// Screening GEMM (unchanged): A-fragments register-resident, B staged 64 KB
// per barrier pair. Per-lane running top-2 packed keys.
__global__ __launch_bounds__(256, 2) void dist_screen_kernel(
    const unsigned short* __restrict__ Xbf,
    const unsigned short* __restrict__ EbfT,
    const float* __restrict__ es2,
    unsigned int* __restrict__ cand) {
    __shared__ __align__(16) unsigned short Bs[32768];   // 64 KB [kb][quad][n][8]

    const int tid  = threadIdx.x;
    const int lane = tid & 63;
    const int wid  = tid >> 6;
    const int wm   = wid >> 1, wn = wid & 1;
    const int col  = lane & 15, quad = lane >> 4;
    const int nbg  = blockIdx.x;           // 0..3
    const int m0   = blockIdx.y * 128;

    short8 af[4][8];
#pragma unroll
    for (int mi = 0; mi < 4; ++mi) {
        const unsigned short* base =
            Xbf + (size_t)(m0 + wm * 64 + mi * 16 + col) * DIM + quad * 8;
#pragma unroll
        for (int kb = 0; kb < 8; ++kb)
            af[mi][kb] = *(const short8*)(base + kb * 32);
    }

    unsigned b1[16], b2[16];
#pragma unroll
    for (int i = 0; i < 16; ++i) { b1[i] = 0xFFFFFFFFu; b2[i] = 0xFFFFFFFFu; }

    const unsigned short* gsrc = EbfT + (size_t)nbg * 16 * 32768 + tid * 8;
    char* ldst = (char*)Bs + tid * 16;

    for (int nt = 0; nt < 16; ++nt) {
        const int n0 = nbg * 2048 + nt * 128;
        __syncthreads();
#pragma unroll
        for (int i = 0; i < 16; ++i)
            gl_lds16(gsrc + (size_t)nt * 32768 + i * 2048, ldst + i * 4096);
        __syncthreads();

        float e_l[4];
#pragma unroll
        for (int ni = 0; ni < 4; ++ni)
            e_l[ni] = es2[n0 + wn * 64 + ni * 16 + col];

#pragma unroll
        for (int nh = 0; nh < 2; ++nh) {
            floatx4 acc[4][2];
#pragma unroll
            for (int mi = 0; mi < 4; ++mi) {
                acc[mi][0] = (floatx4)0.f; acc[mi][1] = (floatx4)0.f;
            }
            const int n_a = wn * 64 + (nh * 2 + 0) * 16 + col;
            const int n_b = wn * 64 + (nh * 2 + 1) * 16 + col;
#pragma unroll
            for (int kb = 0; kb < 8; ++kb) {
                short8 bf0 = *(const short8*)&Bs[kb * 4096 + quad * 1024 + n_a * 8];
                short8 bf1 = *(const short8*)&Bs[kb * 4096 + quad * 1024 + n_b * 8];
#pragma unroll
                for (int mi = 0; mi < 4; ++mi) {
                    acc[mi][0] = __builtin_amdgcn_mfma_f32_16x16x32_bf16(
                        af[mi][kb], bf0, acc[mi][0], 0, 0, 0);
                    acc[mi][1] = __builtin_amdgcn_mfma_f32_16x16x32_bf16(
                        af[mi][kb], bf1, acc[mi][1], 0, 0, 0);
                }
            }
#pragma unroll
            for (int nj = 0; nj < 2; ++nj) {
                int ni = nh * 2 + nj;
                unsigned idxc = (unsigned)(n0 + wn * 64 + ni * 16 + col);
                float e = e_l[ni];
#pragma unroll
                for (int mi = 0; mi < 4; ++mi)
#pragma unroll
                    for (int r = 0; r < 4; ++r) {
                        float d = e + acc[mi][nj][r];
                        unsigned key = ((unsigned)d << 13) + idxc;
                        int s = mi * 4 + r;
                        unsigned lo = umin2(key, b1[s]);
                        unsigned hi = umax2(key, b1[s]);
                        b1[s] = lo;
                        b2[s] = umin2(hi, b2[s]);
                    }
            }
        }
    }

#pragma unroll
    for (int mi = 0; mi < 4; ++mi)
#pragma unroll
        for (int r = 0; r < 4; ++r) {
            int token = m0 + wm * 64 + mi * 16 + quad * 4 + r;
            uint2 v; v.x = b1[mi * 4 + r]; v.y = b2[mi * 4 + r];
            *(uint2*)&cand[(size_t)token * NCAND + nbg * 64 + wn * 32 + col * 2] = v;
        }
}

// ---------------------------------------------------------------------------
// Exact fp32 rescore + quantize write + histogram + diff.
__global__ __launch_bounds__(256) void finalize_kernel(
    const float* __restrict__ x, const float* __restrict__ embedT,
    const float* __restrict__ e2,
    const unsigned int* __restrict__ cand,
    int* __restrict__ ind, float* __restrict__ out) {
    __shared__ float partial[4];
    int tid = threadIdx.x, w = tid >> 6, lane = tid & 63;
    int token = blockIdx.x * 4 + w;

    float4 xv = *(const float4*)&x[(size_t)token * DIM + lane * 4];
    float x2 = xv.x * xv.x + xv.y * xv.y + xv.z * xv.z + xv.w * xv.w;
    uint4 c = *(const uint4*)&cand[(size_t)token * NCAND + lane * 4];
    unsigned g = umin2(umin2(c.x, c.y), umin2(c.z, c.w));
#pragma unroll
    for (int m = 1; m < 64; m <<= 1) {
        x2 += __shfl_xor(x2, m);
        g = umin2(g, (unsigned)__shfl_xor((int)g, m));
    }
    const unsigned thr = g + (384u << 13);   // margin 1.5 in true-dist units

    float bd = 3.4e38f; int bk = 0x7fffffff;
    float4 bq = make_float4(0.f, 0.f, 0.f, 0.f);
    unsigned ca[4] = {c.x, c.y, c.z, c.w};
#pragma unroll
    for (int s = 0; s < 4; ++s) {
        unsigned long long mask = __ballot(ca[s] <= thr);
        while (mask) {
            int l = __ffsll(mask) - 1;
            mask &= mask - 1;
            int k = __shfl((int)ca[s], l) & 8191;
            float4 ev = *(const float4*)&embedT[(size_t)k * DIM + lane * 4];
            float p = xv.x * ev.x;
            p = fmaf(xv.y, ev.y, p);
            p = fmaf(xv.z, ev.z, p);
            p = fmaf(xv.w, ev.w, p);
#pragma unroll
            for (int m = 1; m < 64; m <<= 1) p += __shfl_xor(p, m);
            float d = e2[k] - 2.0f * p;
            if (d < bd || (d == bd && k < bk)) { bd = d; bk = k; bq = ev; }
        }
    }
    *(float4*)&out[OFF_Q + (size_t)token * DIM + lane * 4] = bq;
    if (lane == 0) {
        ind[token] = bk;
        out[OFF_IND + token] = (float)bk;
        atomicAdd(&out[OFF_OH + bk], 1.0f);
        partial[w] = x2 + bd;
    }
    __syncthreads();
    if (tid == 0)
        atomicAdd(&out[OFF_DIFF],
                  (partial[0] + partial[1] + partial[2] + partial[3]) *
                  (1.0f / 4194304.0f));
}

// ---------------------------------------------------------------------------
// Exclusive prefix sum of the 8192 OH counts -> start[], cur[] (one block).
__global__ void scan_kernel(const float* __restrict__ out,
                            int* __restrict__ start, int* __restrict__ cur) {
    __shared__ int ps[256];
    int tid = threadIdx.x;
    int base = tid * 32;
    int loc[32];
    int s = 0;
#pragma unroll
    for (int j = 0; j < 32; ++j) {
        int c = (int)(out[OFF_OH + base + j] + 0.5f);
        loc[j] = s; s += c;
    }
    ps[tid] = s;
    __syncthreads();
    for (int d = 1; d < 256; d <<= 1) {
        int v = (tid >= d) ? ps[tid - d] : 0;
        __syncthreads();
        ps[tid] += v;
        __syncthreads();
    }
    int ex = ps[tid] - s;   // exclusive prefix of this thread's chunk
#pragma unroll
    for (int j = 0; j < 32; ++j) {
        int o = ex + loc[j];
        start[base + j] = o;
        cur[base + j] = o;
    }
}

// ---------------------------------------------------------------------------
// Bucket tokens by code: list[start[k] + slot] = token.  16K atomics total.
__global__ void scatter_kernel(const int* __restrict__ ind,
                               int* __restrict__ cur, int* __restrict__ list) {
    int t = blockIdx.x * 256 + threadIdx.x;
    int k = ind[t];
    int pos = atomicAdd(&cur[k], 1);
    list[pos] = t;
}

// ---------------------------------------------------------------------------
// embed_sum v2: 1024 blocks x 8 codes. One wave per 2 codes. Token ids are
// prefetched lane-parallel (ONE load), then broadcast via readlane so the
// x-row gathers are address-independent and pipeline (R7 version chained
// list->x loads serially at 1 block/CU: 120us, occupancy 1.5%).
__global__ __launch_bounds__(256) void sum_es_kernel(
    const float* __restrict__ x, const float* __restrict__ out_oh,
    const int* __restrict__ start, const int* __restrict__ list,
    float* __restrict__ out) {
    __shared__ float t2[DIM][9];
    int tid = threadIdx.x, w = tid >> 6, lane = tid & 63;
    int k0 = blockIdx.x * 8;
#pragma unroll
    for (int j = 0; j < 2; ++j) {
        int c = j * 4 + w;              // code slot 0..7
        int k = k0 + c;
        int s = start[k];
        int cnt = (int)(out_oh[OFF_OH + k] + 0.5f);
        float4 a = make_float4(0.f, 0.f, 0.f, 0.f);
        for (int base = 0; base < cnt; base += 64) {
            int rem = cnt - base; if (rem > 64) rem = 64;
            int tl = (lane < rem) ? list[s + base + lane] : 0;
            for (int i = 0; i < rem; ++i) {
                int t = __builtin_amdgcn_readlane(tl, i);
                float4 xv = *(const float4*)&x[(size_t)t * DIM + lane * 4];
                a.x += xv.x; a.y += xv.y; a.z += xv.z; a.w += xv.w;
            }
        }
        t2[lane * 4 + 0][c] = a.x;
        t2[lane * 4 + 1][c] = a.y;
        t2[lane * 4 + 2][c] = a.z;
        t2[lane * 4 + 3][c] = a.w;
    }
    __syncthreads();
    // 2048 cells: d = i>>3, c = i&7 -> 32B contiguous segments per d
    for (int t = 0; t < 8; ++t) {
        int i = t * 256 + tid;
        int d = i >> 3, c = i & 7;
        out[OFF_ES + (size_t)d * NE + k0 + c] = t2[d][c];
    }
}

// ===========================================================================
extern "C" void kernel_launch(void* const* d_in, const int* in_sizes, int n_in,
                              void* d_out, int out_size, void* d_ws, size_t ws_size,
                              hipStream_t stream) {
    const float* x     = (const float*)d_in[0];
    const float* embed = (const float*)d_in[1];
    float* out = (float*)d_out;

    // ws layout (~38 MB)
    char* p = (char*)d_ws;
    unsigned short* Xbf  = (unsigned short*)p;  p += (size_t)NTOK * DIM * 2;    // 8.4 MB
    unsigned short* EbfT = (unsigned short*)p;  p += (size_t)NE * DIM * 2;      // 4.2 MB (tiled)
    float* embedT = (float*)p;                  p += (size_t)NE * DIM * 4;      // 8.4 MB
    float* e2     = (float*)p;                  p += (size_t)NE * 4;
    float* es2    = (float*)p;                  p += (size_t)NE * 4;
    unsigned int* cand = (unsigned int*)p;      p += (size_t)NTOK * NCAND * 4;  // 16.8 MB
    int*   ind    = (int*)p;                    p += (size_t)NTOK * 4;
    int*   start  = (int*)p;                    p += (size_t)NE * 4;
    int*   cur    = (int*)p;                    p += (size_t)NE * 4;
    int*   list   = (int*)p;                    p += (size_t)NTOK * 4;

    // zero DIFF/IND/OH header (Q and ES are fully overwritten)
    hipMemsetAsync((char*)d_out + (size_t)OFF_DIFF * 4, 0,
                   ((size_t)(OFF_ES - OFF_DIFF)) * 4, stream);

    convert_x_kernel<<<(NTOK * DIM / 4) / 256, 256, 0, stream>>>(x, Xbf);
    convert_e_kernel<<<NE / 32, 256, 0, stream>>>(embed, EbfT, embedT, e2, es2);
    dist_screen_kernel<<<dim3(4, NTOK / 128), 256, 0, stream>>>(
        Xbf, EbfT, es2, cand);
    finalize_kernel<<<NTOK / 4, 256, 0, stream>>>(
        x, embedT, e2, cand, ind, out);
    scan_kernel<<<1, 256, 0, stream>>>(out, start, cur);
    scatter_kernel<<<NTOK / 256, 256, 0, stream>>>(ind, cur, list);
    sum_es_kernel<<<NE / 8, 256, 0, stream>>>(x, out, start, list, out);
}

// Round 9
// 254.619 us; speedup vs baseline: 1.3332x; 1.2847x over previous
//
#include <hip/hip_runtime.h>

#define DIM   256
#define NE    8192
#define NTOK  16384

// d_out flat offsets (floats)
#define OFF_Q    0
#define OFF_DIFF 4194304
#define OFF_IND  4194305
#define OFF_OH   4210689
#define OFF_ES   4218881

#define NCAND 256     // keys per token: 4 nbg x 2 wn x 16 col x top-2

typedef __attribute__((ext_vector_type(8))) short short8;
typedef __attribute__((ext_vector_type(4))) float floatx4;

__device__ inline unsigned umin2(unsigned a, unsigned b) { return a < b ? a : b; }
__device__ inline unsigned umax2(unsigned a, unsigned b) { return a > b ? a : b; }

__device__ inline void gl_lds16(const void* g, void* l) {
    __builtin_amdgcn_global_load_lds(
        (const __attribute__((address_space(1))) unsigned int*)g,
        (__attribute__((address_space(3))) unsigned int*)l, 16, 0, 0);
}

__device__ inline unsigned short b16rn(float f) {
    unsigned u = __float_as_uint(f);
    unsigned r = (u + 0x7fffu + ((u >> 16) & 1u)) >> 16;
    return (unsigned short)r;
}

// ---------------------------------------------------------------------------
// Xbf[m][d] = bf16(x[m][d])
__global__ void convert_x_kernel(const float* __restrict__ x,
                                 unsigned short* __restrict__ Xbf) {
    int i = blockIdx.x * 256 + threadIdx.x;   // float4 index
    float4 v = ((const float4*)x)[i];
    ushort4 h;
    h.x = b16rn(v.x); h.y = b16rn(v.y); h.z = b16rn(v.z); h.w = b16rn(v.w);
    ((ushort4*)Xbf)[i] = h;
}

// ---------------------------------------------------------------------------
// convert_e: embed -> EbfT tiled bf16(-512*e) [tile128][kb8][quad4][n128][8],
// embedT fp32 [n][d], e2 / es2 per code.
__global__ void convert_e_kernel(const float* __restrict__ embed,
                                 unsigned short* __restrict__ EbfT,
                                 float* __restrict__ embedT,
                                 float* __restrict__ e2,
                                 float* __restrict__ es2) {
    __shared__ __align__(16) float t2[32][DIM + 4];
    __shared__ float red[32][8];
    int c0 = blockIdx.x * 32;
    int tid = threadIdx.x;
    for (int t = 0; t < 32; ++t) {
        int i = t * 256 + tid;
        int d = i >> 5, c = i & 31;
        t2[c][d] = embed[(size_t)d * NE + c0 + c];
    }
    __syncthreads();
    for (int t = 0; t < 8; ++t) {
        int i = t * 256 + tid;          // 0..2047 float4 units
        int c = i >> 6, dq = i & 63;
        float4 v = *(const float4*)&t2[c][dq * 4];
        *(float4*)&embedT[(size_t)(c0 + c) * DIM + dq * 4] = v;
        ushort4 h;
        h.x = b16rn(-512.0f * v.x); h.y = b16rn(-512.0f * v.y);
        h.z = b16rn(-512.0f * v.z); h.w = b16rn(-512.0f * v.w);
        int C = c0 + c;
        int nb = C >> 7, n = C & 127;
        size_t off = (size_t)nb * 32768 + (size_t)(dq >> 3) * 4096 +
                     (size_t)((dq >> 1) & 3) * 1024 + (size_t)n * 8 + (dq & 1) * 4;
        *(ushort4*)&EbfT[off] = h;
    }
    {
        int c = tid >> 3, seg = tid & 7;
        float s = 0.f;
        for (int d = seg * 32; d < seg * 32 + 32; ++d)
            s = fmaf(t2[c][d], t2[c][d], s);
        red[c][seg] = s;
    }
    __syncthreads();
    if (tid < 32) {
        float s = 0.f;
        for (int j = 0; j < 8; ++j) s += red[tid][j];
        e2[c0 + tid] = s;
        es2[c0 + tid] = 256.0f * (512.0f + s);
    }
}

// ---------------------------------------------------------------------------
// Screening GEMM (unchanged): A-fragments register-resident, B staged 64 KB
// per barrier pair. Per-lane running top-2 packed keys.
__global__ __launch_bounds__(256, 2) void dist_screen_kernel(
    const unsigned short* __restrict__ Xbf,
    const unsigned short* __restrict__ EbfT,
    const float* __restrict__ es2,
    unsigned int* __restrict__ cand) {
    __shared__ __align__(16) unsigned short Bs[32768];   // 64 KB [kb][quad][n][8]

    const int tid  = threadIdx.x;
    const int lane = tid & 63;
    const int wid  = tid >> 6;
    const int wm   = wid >> 1, wn = wid & 1;
    const int col  = lane & 15, quad = lane >> 4;
    const int nbg  = blockIdx.x;           // 0..3
    const int m0   = blockIdx.y * 128;

    short8 af[4][8];
#pragma unroll
    for (int mi = 0; mi < 4; ++mi) {
        const unsigned short* base =
            Xbf + (size_t)(m0 + wm * 64 + mi * 16 + col) * DIM + quad * 8;
#pragma unroll
        for (int kb = 0; kb < 8; ++kb)
            af[mi][kb] = *(const short8*)(base + kb * 32);
    }

    unsigned b1[16], b2[16];
#pragma unroll
    for (int i = 0; i < 16; ++i) { b1[i] = 0xFFFFFFFFu; b2[i] = 0xFFFFFFFFu; }

    const unsigned short* gsrc = EbfT + (size_t)nbg * 16 * 32768 + tid * 8;
    char* ldst = (char*)Bs + tid * 16;

    for (int nt = 0; nt < 16; ++nt) {
        const int n0 = nbg * 2048 + nt * 128;
        __syncthreads();
#pragma unroll
        for (int i = 0; i < 16; ++i)
            gl_lds16(gsrc + (size_t)nt * 32768 + i * 2048, ldst + i * 4096);
        __syncthreads();

        float e_l[4];
#pragma unroll
        for (int ni = 0; ni < 4; ++ni)
            e_l[ni] = es2[n0 + wn * 64 + ni * 16 + col];

#pragma unroll
        for (int nh = 0; nh < 2; ++nh) {
            floatx4 acc[4][2];
#pragma unroll
            for (int mi = 0; mi < 4; ++mi) {
                acc[mi][0] = (floatx4)0.f; acc[mi][1] = (floatx4)0.f;
            }
            const int n_a = wn * 64 + (nh * 2 + 0) * 16 + col;
            const int n_b = wn * 64 + (nh * 2 + 1) * 16 + col;
#pragma unroll
            for (int kb = 0; kb < 8; ++kb) {
                short8 bf0 = *(const short8*)&Bs[kb * 4096 + quad * 1024 + n_a * 8];
                short8 bf1 = *(const short8*)&Bs[kb * 4096 + quad * 1024 + n_b * 8];
#pragma unroll
                for (int mi = 0; mi < 4; ++mi) {
                    acc[mi][0] = __builtin_amdgcn_mfma_f32_16x16x32_bf16(
                        af[mi][kb], bf0, acc[mi][0], 0, 0, 0);
                    acc[mi][1] = __builtin_amdgcn_mfma_f32_16x16x32_bf16(
                        af[mi][kb], bf1, acc[mi][1], 0, 0, 0);
                }
            }
#pragma unroll
            for (int nj = 0; nj < 2; ++nj) {
                int ni = nh * 2 + nj;
                unsigned idxc = (unsigned)(n0 + wn * 64 + ni * 16 + col);
                float e = e_l[ni];
#pragma unroll
                for (int mi = 0; mi < 4; ++mi)
#pragma unroll
                    for (int r = 0; r < 4; ++r) {
                        float d = e + acc[mi][nj][r];
                        unsigned key = ((unsigned)d << 13) + idxc;
                        int s = mi * 4 + r;
                        unsigned lo = umin2(key, b1[s]);
                        unsigned hi = umax2(key, b1[s]);
                        b1[s] = lo;
                        b2[s] = umin2(hi, b2[s]);
                    }
            }
        }
    }

#pragma unroll
    for (int mi = 0; mi < 4; ++mi)
#pragma unroll
        for (int r = 0; r < 4; ++r) {
            int token = m0 + wm * 64 + mi * 16 + quad * 4 + r;
            uint2 v; v.x = b1[mi * 4 + r]; v.y = b2[mi * 4 + r];
            *(uint2*)&cand[(size_t)token * NCAND + nbg * 64 + wn * 32 + col * 2] = v;
        }
}

// ---------------------------------------------------------------------------
// Exact fp32 rescore + quantize write + histogram + diff.
__global__ __launch_bounds__(256) void finalize_kernel(
    const float* __restrict__ x, const float* __restrict__ embedT,
    const float* __restrict__ e2,
    const unsigned int* __restrict__ cand,
    int* __restrict__ ind, float* __restrict__ out) {
    __shared__ float partial[4];
    int tid = threadIdx.x, w = tid >> 6, lane = tid & 63;
    int token = blockIdx.x * 4 + w;

    float4 xv = *(const float4*)&x[(size_t)token * DIM + lane * 4];
    float x2 = xv.x * xv.x + xv.y * xv.y + xv.z * xv.z + xv.w * xv.w;
    uint4 c = *(const uint4*)&cand[(size_t)token * NCAND + lane * 4];
    unsigned g = umin2(umin2(c.x, c.y), umin2(c.z, c.w));
#pragma unroll
    for (int m = 1; m < 64; m <<= 1) {
        x2 += __shfl_xor(x2, m);
        g = umin2(g, (unsigned)__shfl_xor((int)g, m));
    }
    const unsigned thr = g + (384u << 13);   // margin 1.5 in true-dist units

    float bd = 3.4e38f; int bk = 0x7fffffff;
    float4 bq = make_float4(0.f, 0.f, 0.f, 0.f);
    unsigned ca[4] = {c.x, c.y, c.z, c.w};
#pragma unroll
    for (int s = 0; s < 4; ++s) {
        unsigned long long mask = __ballot(ca[s] <= thr);
        while (mask) {
            int l = __ffsll(mask) - 1;
            mask &= mask - 1;
            int k = __shfl((int)ca[s], l) & 8191;
            float4 ev = *(const float4*)&embedT[(size_t)k * DIM + lane * 4];
            float p = xv.x * ev.x;
            p = fmaf(xv.y, ev.y, p);
            p = fmaf(xv.z, ev.z, p);
            p = fmaf(xv.w, ev.w, p);
#pragma unroll
            for (int m = 1; m < 64; m <<= 1) p += __shfl_xor(p, m);
            float d = e2[k] - 2.0f * p;
            if (d < bd || (d == bd && k < bk)) { bd = d; bk = k; bq = ev; }
        }
    }
    *(float4*)&out[OFF_Q + (size_t)token * DIM + lane * 4] = bq;
    if (lane == 0) {
        ind[token] = bk;
        out[OFF_IND + token] = (float)bk;
        atomicAdd(&out[OFF_OH + bk], 1.0f);
        partial[w] = x2 + bd;
    }
    __syncthreads();
    if (tid == 0)
        atomicAdd(&out[OFF_DIFF],
                  (partial[0] + partial[1] + partial[2] + partial[3]) *
                  (1.0f / 4194304.0f));
}

// ---------------------------------------------------------------------------
// Prefix sums over 8192 OH counts -> start[]/cur[], AND the chunk work queue:
// one item per (code, 16-token chunk), work = k | ci<<13 | (n-1)<<23 | single<<27.
__global__ void scan_kernel(const float* __restrict__ outoh,
                            int* __restrict__ start, int* __restrict__ cur,
                            int* __restrict__ work, int* __restrict__ nwork) {
    __shared__ int ps[256];
    __shared__ int pc[256];
    int tid = threadIdx.x;
    int base = tid * 32;
    int cnts[32], loc[32];
    int s = 0, ch = 0;
#pragma unroll
    for (int j = 0; j < 32; ++j) {
        int c = (int)(outoh[OFF_OH + base + j] + 0.5f);
        cnts[j] = c; loc[j] = s; s += c; ch += (c + 15) >> 4;
    }
    ps[tid] = s; pc[tid] = ch;
    __syncthreads();
    for (int d = 1; d < 256; d <<= 1) {
        int v1 = (tid >= d) ? ps[tid - d] : 0;
        int v2 = (tid >= d) ? pc[tid - d] : 0;
        __syncthreads();
        ps[tid] += v1; pc[tid] += v2;
        __syncthreads();
    }
    int exs = ps[tid] - s;
    int wk  = pc[tid] - ch;
#pragma unroll
    for (int j = 0; j < 32; ++j) {
        int o = exs + loc[j];
        start[base + j] = o;
        cur[base + j] = o;
        int c = cnts[j];
        int nch = (c + 15) >> 4;
        int single = (nch == 1) ? 1 : 0;
        for (int ci = 0; ci < nch; ++ci) {
            int n = c - ci * 16; if (n > 16) n = 16;
            work[wk++] = (base + j) | (ci << 13) | ((n - 1) << 23) | (single << 27);
        }
    }
    if (tid == 255) nwork[0] = pc[255];
}

// ---------------------------------------------------------------------------
// Bucket tokens by code: list[start[k] + slot] = token.  16K atomics total.
__global__ void scatter_kernel(const int* __restrict__ ind,
                               int* __restrict__ cur, int* __restrict__ list) {
    int t = blockIdx.x * 256 + threadIdx.x;
    int k = ind[t];
    int pos = atomicAdd(&cur[k], 1);
    list[pos] = t;
}

// ---------------------------------------------------------------------------
// embed_sum v3: one wave per 16-token chunk (work queue). 16 broadcast id
// loads then 16 independent unrolled float4 row loads (real MLP, ~64 VGPRs of
// payload). Single-chunk codes plain-store their esT row; multi-chunk codes
// atomicAdd onto memset-zeroed esT. Straggler capped at 16 rows per wave.
__global__ __launch_bounds__(256) void sum_es_kernel(
    const float* __restrict__ x, const int* __restrict__ start,
    const int* __restrict__ list, const int* __restrict__ work,
    const int* __restrict__ nwork, float* __restrict__ esT) {
    int tid = threadIdx.x, w = tid >> 6, lane = tid & 63;
    int wi = blockIdx.x * 4 + w;
    if (wi >= nwork[0]) return;
    int e = work[wi];
    int k      = e & 8191;
    int ci     = (e >> 13) & 1023;
    int n      = ((e >> 23) & 15) + 1;
    int single = (e >> 27) & 1;
    int s = start[k] + ci * 16;

    int ids[16];
#pragma unroll
    for (int i = 0; i < 16; ++i) ids[i] = list[s + i];   // list padded by 16

    float4 acc = make_float4(0.f, 0.f, 0.f, 0.f);
#pragma unroll
    for (int i = 0; i < 16; ++i) {
        int t = (i < n) ? ids[i] : ids[0];
        float4 v = *(const float4*)&x[(size_t)t * DIM + lane * 4];
        if (i < n) { acc.x += v.x; acc.y += v.y; acc.z += v.z; acc.w += v.w; }
    }

    float* dst = &esT[(size_t)k * DIM + lane * 4];
    if (single) {
        *(float4*)dst = acc;
    } else {
        atomicAdd(dst + 0, acc.x);
        atomicAdd(dst + 1, acc.y);
        atomicAdd(dst + 2, acc.z);
        atomicAdd(dst + 3, acc.w);
    }
}

// ---------------------------------------------------------------------------
// out[OFF_ES + d*NE + k] = esT[k][d]  (coalesced transpose, 16 codes/block)
__global__ void es_out_kernel(const float* __restrict__ esT,
                              float* __restrict__ out) {
    __shared__ float t2[DIM][17];
    int k0 = blockIdx.x * 16;
    int tid = threadIdx.x;
    for (int t = 0; t < 4; ++t) {
        int i = t * 256 + tid;          // 1024 float4 units over 16x64
        int k = i >> 6, dq = i & 63;
        float4 v = ((const float4*)esT)[(size_t)(k0 + k) * 64 + dq];
        t2[dq * 4 + 0][k] = v.x;
        t2[dq * 4 + 1][k] = v.y;
        t2[dq * 4 + 2][k] = v.z;
        t2[dq * 4 + 3][k] = v.w;
    }
    __syncthreads();
    for (int t = 0; t < 16; ++t) {
        int i = t * 256 + tid;          // 4096 cells: d = i>>4, c = i&15
        int d = i >> 4, c = i & 15;
        out[OFF_ES + (size_t)d * NE + k0 + c] = t2[d][c];
    }
}

// ===========================================================================
extern "C" void kernel_launch(void* const* d_in, const int* in_sizes, int n_in,
                              void* d_out, int out_size, void* d_ws, size_t ws_size,
                              hipStream_t stream) {
    const float* x     = (const float*)d_in[0];
    const float* embed = (const float*)d_in[1];
    float* out = (float*)d_out;

    // ws layout (~47 MB)
    char* p = (char*)d_ws;
    unsigned short* Xbf  = (unsigned short*)p;  p += (size_t)NTOK * DIM * 2;    // 8.4 MB
    unsigned short* EbfT = (unsigned short*)p;  p += (size_t)NE * DIM * 2;      // 4.2 MB (tiled)
    float* embedT = (float*)p;                  p += (size_t)NE * DIM * 4;      // 8.4 MB
    float* e2     = (float*)p;                  p += (size_t)NE * 4;
    float* es2    = (float*)p;                  p += (size_t)NE * 4;
    unsigned int* cand = (unsigned int*)p;      p += (size_t)NTOK * NCAND * 4;  // 16.8 MB
    int*   ind    = (int*)p;                    p += (size_t)NTOK * 4;
    int*   start  = (int*)p;                    p += (size_t)NE * 4;
    int*   cur    = (int*)p;                    p += (size_t)NE * 4;
    int*   list   = (int*)p;                    p += (size_t)(NTOK + 16) * 4;   // +16 pad
    int*   work   = (int*)p;                    p += (size_t)16384 * 4;
    int*   nwork  = (int*)p;                    p += 64;
    float* esT    = (float*)p;                  p += (size_t)NE * DIM * 4;      // 8.4 MB

    // zero DIFF/IND/OH header (Q and ES fully overwritten) + esT accumulator
    hipMemsetAsync((char*)d_out + (size_t)OFF_DIFF * 4, 0,
                   ((size_t)(OFF_ES - OFF_DIFF)) * 4, stream);
    hipMemsetAsync(esT, 0, (size_t)NE * DIM * 4, stream);

    convert_x_kernel<<<(NTOK * DIM / 4) / 256, 256, 0, stream>>>(x, Xbf);
    convert_e_kernel<<<NE / 32, 256, 0, stream>>>(embed, EbfT, embedT, e2, es2);
    dist_screen_kernel<<<dim3(4, NTOK / 128), 256, 0, stream>>>(
        Xbf, EbfT, es2, cand);
    finalize_kernel<<<NTOK / 4, 256, 0, stream>>>(
        x, embedT, e2, cand, ind, out);
    scan_kernel<<<1, 256, 0, stream>>>(out, start, cur, work, nwork);
    scatter_kernel<<<NTOK / 256, 256, 0, stream>>>(ind, cur, list);
    sum_es_kernel<<<2304, 256, 0, stream>>>(x, start, list, work, nwork, esT);
    es_out_kernel<<<NE / 16, 256, 0, stream>>>(esT, out);
}

// Round 10
// 250.642 us; speedup vs baseline: 1.3543x; 1.0159x over previous
//
#include <hip/hip_runtime.h>

#define DIM   256
#define NE    8192
#define NTOK  16384

// d_out flat offsets (floats)
#define OFF_Q    0
#define OFF_DIFF 4194304
#define OFF_IND  4194305
#define OFF_OH   4210689
#define OFF_ES   4218881

#define NCAND 256     // keys per token: 4 nbg x 2 wn x 16 col x top-2

typedef __attribute__((ext_vector_type(8))) short short8;
typedef __attribute__((ext_vector_type(4))) float floatx4;

__device__ inline unsigned umin2(unsigned a, unsigned b) { return a < b ? a : b; }
__device__ inline unsigned umax2(unsigned a, unsigned b) { return a > b ? a : b; }

__device__ inline void gl_lds16(const void* g, void* l) {
    __builtin_amdgcn_global_load_lds(
        (const __attribute__((address_space(1))) unsigned int*)g,
        (__attribute__((address_space(3))) unsigned int*)l, 16, 0, 0);
}

__device__ inline unsigned short b16rn(float f) {
    unsigned u = __float_as_uint(f);
    unsigned r = (u + 0x7fffu + ((u >> 16) & 1u)) >> 16;
    return (unsigned short)r;
}

// ---------------------------------------------------------------------------
// Xbf[m][d] = bf16(x[m][d])
__global__ void convert_x_kernel(const float* __restrict__ x,
                                 unsigned short* __restrict__ Xbf) {
    int i = blockIdx.x * 256 + threadIdx.x;   // float4 index
    float4 v = ((const float4*)x)[i];
    ushort4 h;
    h.x = b16rn(v.x); h.y = b16rn(v.y); h.z = b16rn(v.z); h.w = b16rn(v.w);
    ((ushort4*)Xbf)[i] = h;
}

// ---------------------------------------------------------------------------
// convert_e: embed -> EbfT tiled bf16(-512*e) in 64-code-tile order
// [tile64][kb8][quad4][n64][8] (matches dist_screen staging+fragment reads),
// embedT fp32 [n][d], e2 / es2 per code.
__global__ void convert_e_kernel(const float* __restrict__ embed,
                                 unsigned short* __restrict__ EbfT,
                                 float* __restrict__ embedT,
                                 float* __restrict__ e2,
                                 float* __restrict__ es2) {
    __shared__ __align__(16) float t2[32][DIM + 4];
    __shared__ float red[32][8];
    int c0 = blockIdx.x * 32;
    int tid = threadIdx.x;
    for (int t = 0; t < 32; ++t) {
        int i = t * 256 + tid;
        int d = i >> 5, c = i & 31;
        t2[c][d] = embed[(size_t)d * NE + c0 + c];
    }
    __syncthreads();
    for (int t = 0; t < 8; ++t) {
        int i = t * 256 + tid;          // 0..2047 float4 units
        int c = i >> 6, dq = i & 63;    // code-local, k-quad (k = 4*dq)
        float4 v = *(const float4*)&t2[c][dq * 4];
        *(float4*)&embedT[(size_t)(c0 + c) * DIM + dq * 4] = v;
        ushort4 h;
        h.x = b16rn(-512.0f * v.x); h.y = b16rn(-512.0f * v.y);
        h.z = b16rn(-512.0f * v.z); h.w = b16rn(-512.0f * v.w);
        int C = c0 + c;
        // 64-code tile layout: tile=C>>6, kb=dq>>3, quad=(dq>>1)&3, n=C&63, j=(dq&1)*4
        size_t off = (size_t)(C >> 6) * 16384 + (size_t)(dq >> 3) * 2048 +
                     (size_t)((dq >> 1) & 3) * 512 + (size_t)(C & 63) * 8 + (dq & 1) * 4;
        *(ushort4*)&EbfT[off] = h;
    }
    {
        int c = tid >> 3, seg = tid & 7;
        float s = 0.f;
        for (int d = seg * 32; d < seg * 32 + 32; ++d)
            s = fmaf(t2[c][d], t2[c][d], s);
        red[c][seg] = s;
    }
    __syncthreads();
    if (tid < 32) {
        float s = 0.f;
        for (int j = 0; j < 8; ++j) s += red[tid][j];
        e2[c0 + tid] = s;
        es2[c0 + tid] = 256.0f * (512.0f + s);
    }
}

// ---------------------------------------------------------------------------
// Screening GEMM v3: A-fragments register-resident (waves_per_eu(2,2) frees
// the 256-VGPR budget; R9's 120-VGPR cap forced per-tile A reloads), B double-
// buffered 2x32KB 64-code tiles — stage of tile nt+1 issued right after the
// barrier consuming tile nt, so the drain is hidden behind a full compute
// phase (ONE barrier per tile). es2 is MFMA C-init (acc starts at es2).
__global__ __launch_bounds__(256)
__attribute__((amdgpu_waves_per_eu(2, 2)))
void dist_screen_kernel(
    const unsigned short* __restrict__ Xbf,
    const unsigned short* __restrict__ EbfT,
    const float* __restrict__ es2,
    unsigned int* __restrict__ cand) {
    __shared__ __align__(16) unsigned short Bs[2][16384];  // 2 x 32 KB
    __shared__ __align__(16) float esL[2048];              // 8 KB

    const int tid  = threadIdx.x;
    const int lane = tid & 63;
    const int wid  = tid >> 6;
    const int wm   = wid >> 1, wn = wid & 1;
    const int col  = lane & 15, quad = lane >> 4;
    const int nbg  = blockIdx.x;           // 0..3
    const int m0   = blockIdx.y * 128;

    // A fragments, register-resident for all 32 tiles
    short8 af[4][8];
#pragma unroll
    for (int mi = 0; mi < 4; ++mi) {
        const unsigned short* base =
            Xbf + (size_t)(m0 + wm * 64 + mi * 16 + col) * DIM + quad * 8;
#pragma unroll
        for (int kb = 0; kb < 8; ++kb)
            af[mi][kb] = *(const short8*)(base + kb * 32);
    }

    unsigned b1[16], b2[16];
#pragma unroll
    for (int i = 0; i < 16; ++i) { b1[i] = 0xFFFFFFFFu; b2[i] = 0xFFFFFFFFu; }

    const unsigned short* gts = EbfT + (size_t)nbg * 32 * 16384;

    // prologue: stage es2 slice (8 KB) + tile 0
#pragma unroll
    for (int p = 0; p < 2; ++p)
        gl_lds16(es2 + nbg * 2048 + p * 1024 + tid * 4,
                 (char*)esL + p * 4096 + tid * 16);
#pragma unroll
    for (int i = 0; i < 8; ++i)
        gl_lds16(gts + tid * 8 + i * 2048, (char*)Bs[0] + tid * 16 + i * 4096);

    for (int nt = 0; nt < 32; ++nt) {
        const int cur = nt & 1;
        __syncthreads();   // drains stage(nt) — issued one full compute ago
        if (nt + 1 < 32) {
            const unsigned short* src = gts + (size_t)(nt + 1) * 16384 + tid * 8;
            char* dst = (char*)Bs[cur ^ 1] + tid * 16;
#pragma unroll
            for (int i = 0; i < 8; ++i)
                gl_lds16(src + i * 2048, dst + i * 4096);
        }

        float e_l0 = esL[nt * 64 + wn * 32 + col];
        float e_l1 = esL[nt * 64 + wn * 32 + 16 + col];
        floatx4 acc[4][2];
#pragma unroll
        for (int mi = 0; mi < 4; ++mi) {
            acc[mi][0] = (floatx4)e_l0;   // es2 folded into C-init
            acc[mi][1] = (floatx4)e_l1;
        }
        const int na = (wn * 32 + col) * 8;
        const int nb2 = (wn * 32 + 16 + col) * 8;
#pragma unroll
        for (int kb = 0; kb < 8; ++kb) {
            short8 bf0 = *(const short8*)&Bs[cur][kb * 2048 + quad * 512 + na];
            short8 bf1 = *(const short8*)&Bs[cur][kb * 2048 + quad * 512 + nb2];
#pragma unroll
            for (int mi = 0; mi < 4; ++mi) {
                acc[mi][0] = __builtin_amdgcn_mfma_f32_16x16x32_bf16(
                    af[mi][kb], bf0, acc[mi][0], 0, 0, 0);
                acc[mi][1] = __builtin_amdgcn_mfma_f32_16x16x32_bf16(
                    af[mi][kb], bf1, acc[mi][1], 0, 0, 0);
            }
        }

        const int n0 = nbg * 2048 + nt * 64;
#pragma unroll
        for (int nj = 0; nj < 2; ++nj) {
            unsigned idxc = (unsigned)(n0 + wn * 32 + nj * 16 + col);
#pragma unroll
            for (int mi = 0; mi < 4; ++mi)
#pragma unroll
                for (int r = 0; r < 4; ++r) {
                    unsigned key = (((unsigned)acc[mi][nj][r]) << 13) + idxc;
                    int s = mi * 4 + r;
                    unsigned lo = umin2(key, b1[s]);
                    unsigned hi = umax2(key, b1[s]);
                    b1[s] = lo;
                    b2[s] = umin2(hi, b2[s]);
                }
        }
    }

#pragma unroll
    for (int mi = 0; mi < 4; ++mi)
#pragma unroll
        for (int r = 0; r < 4; ++r) {
            int token = m0 + wm * 64 + mi * 16 + quad * 4 + r;
            uint2 v; v.x = b1[mi * 4 + r]; v.y = b2[mi * 4 + r];
            *(uint2*)&cand[(size_t)token * NCAND + nbg * 64 + wn * 32 + col * 2] = v;
        }
}

// ---------------------------------------------------------------------------
// Exact fp32 rescore + quantize write + histogram + diff.
__global__ __launch_bounds__(256) void finalize_kernel(
    const float* __restrict__ x, const float* __restrict__ embedT,
    const float* __restrict__ e2,
    const unsigned int* __restrict__ cand,
    int* __restrict__ ind, float* __restrict__ out) {
    __shared__ float partial[4];
    int tid = threadIdx.x, w = tid >> 6, lane = tid & 63;
    int token = blockIdx.x * 4 + w;

    float4 xv = *(const float4*)&x[(size_t)token * DIM + lane * 4];
    float x2 = xv.x * xv.x + xv.y * xv.y + xv.z * xv.z + xv.w * xv.w;
    uint4 c = *(const uint4*)&cand[(size_t)token * NCAND + lane * 4];
    unsigned g = umin2(umin2(c.x, c.y), umin2(c.z, c.w));
#pragma unroll
    for (int m = 1; m < 64; m <<= 1) {
        x2 += __shfl_xor(x2, m);
        g = umin2(g, (unsigned)__shfl_xor((int)g, m));
    }
    const unsigned thr = g + (384u << 13);   // margin 1.5 in true-dist units

    float bd = 3.4e38f; int bk = 0x7fffffff;
    float4 bq = make_float4(0.f, 0.f, 0.f, 0.f);
    unsigned ca[4] = {c.x, c.y, c.z, c.w};
#pragma unroll
    for (int s = 0; s < 4; ++s) {
        unsigned long long mask = __ballot(ca[s] <= thr);
        while (mask) {
            int l = __ffsll(mask) - 1;
            mask &= mask - 1;
            int k = __shfl((int)ca[s], l) & 8191;
            float4 ev = *(const float4*)&embedT[(size_t)k * DIM + lane * 4];
            float p = xv.x * ev.x;
            p = fmaf(xv.y, ev.y, p);
            p = fmaf(xv.z, ev.z, p);
            p = fmaf(xv.w, ev.w, p);
#pragma unroll
            for (int m = 1; m < 64; m <<= 1) p += __shfl_xor(p, m);
            float d = e2[k] - 2.0f * p;
            if (d < bd || (d == bd && k < bk)) { bd = d; bk = k; bq = ev; }
        }
    }
    *(float4*)&out[OFF_Q + (size_t)token * DIM + lane * 4] = bq;
    if (lane == 0) {
        ind[token] = bk;
        out[OFF_IND + token] = (float)bk;
        atomicAdd(&out[OFF_OH + bk], 1.0f);
        partial[w] = x2 + bd;
    }
    __syncthreads();
    if (tid == 0)
        atomicAdd(&out[OFF_DIFF],
                  (partial[0] + partial[1] + partial[2] + partial[3]) *
                  (1.0f / 4194304.0f));
}

// ---------------------------------------------------------------------------
// Prefix sums over 8192 OH counts -> start[]/cur[], AND the chunk work queue:
// one item per (code, 16-token chunk), work = k | ci<<13 | (n-1)<<23 | single<<27.
__global__ void scan_kernel(const float* __restrict__ outoh,
                            int* __restrict__ start, int* __restrict__ cur,
                            int* __restrict__ work, int* __restrict__ nwork) {
    __shared__ int ps[256];
    __shared__ int pc[256];
    int tid = threadIdx.x;
    int base = tid * 32;
    int cnts[32], loc[32];
    int s = 0, ch = 0;
#pragma unroll
    for (int j = 0; j < 32; ++j) {
        int c = (int)(outoh[OFF_OH + base + j] + 0.5f);
        cnts[j] = c; loc[j] = s; s += c; ch += (c + 15) >> 4;
    }
    ps[tid] = s; pc[tid] = ch;
    __syncthreads();
    for (int d = 1; d < 256; d <<= 1) {
        int v1 = (tid >= d) ? ps[tid - d] : 0;
        int v2 = (tid >= d) ? pc[tid - d] : 0;
        __syncthreads();
        ps[tid] += v1; pc[tid] += v2;
        __syncthreads();
    }
    int exs = ps[tid] - s;
    int wk  = pc[tid] - ch;
#pragma unroll
    for (int j = 0; j < 32; ++j) {
        int o = exs + loc[j];
        start[base + j] = o;
        cur[base + j] = o;
        int c = cnts[j];
        int nch = (c + 15) >> 4;
        int single = (nch == 1) ? 1 : 0;
        for (int ci = 0; ci < nch; ++ci) {
            int n = c - ci * 16; if (n > 16) n = 16;
            work[wk++] = (base + j) | (ci << 13) | ((n - 1) << 23) | (single << 27);
        }
    }
    if (tid == 255) nwork[0] = pc[255];
}

// ---------------------------------------------------------------------------
// Bucket tokens by code: list[start[k] + slot] = token.  16K atomics total.
__global__ void scatter_kernel(const int* __restrict__ ind,
                               int* __restrict__ cur, int* __restrict__ list) {
    int t = blockIdx.x * 256 + threadIdx.x;
    int k = ind[t];
    int pos = atomicAdd(&cur[k], 1);
    list[pos] = t;
}

// ---------------------------------------------------------------------------
// embed_sum: one wave per 16-token chunk (work queue); independent row loads;
// single-chunk codes store, multi-chunk codes atomicAdd (rare).
__global__ __launch_bounds__(256) void sum_es_kernel(
    const float* __restrict__ x, const int* __restrict__ start,
    const int* __restrict__ list, const int* __restrict__ work,
    const int* __restrict__ nwork, float* __restrict__ esT) {
    int tid = threadIdx.x, w = tid >> 6, lane = tid & 63;
    int wi = blockIdx.x * 4 + w;
    if (wi >= nwork[0]) return;
    int e = work[wi];
    int k      = e & 8191;
    int ci     = (e >> 13) & 1023;
    int n      = ((e >> 23) & 15) + 1;
    int single = (e >> 27) & 1;
    int s = start[k] + ci * 16;

    int ids[16];
#pragma unroll
    for (int i = 0; i < 16; ++i) ids[i] = list[s + i];   // list padded by 16

    float4 acc = make_float4(0.f, 0.f, 0.f, 0.f);
#pragma unroll
    for (int i = 0; i < 16; ++i) {
        int t = (i < n) ? ids[i] : ids[0];
        float4 v = *(const float4*)&x[(size_t)t * DIM + lane * 4];
        if (i < n) { acc.x += v.x; acc.y += v.y; acc.z += v.z; acc.w += v.w; }
    }

    float* dst = &esT[(size_t)k * DIM + lane * 4];
    if (single) {
        *(float4*)dst = acc;
    } else {
        atomicAdd(dst + 0, acc.x);
        atomicAdd(dst + 1, acc.y);
        atomicAdd(dst + 2, acc.z);
        atomicAdd(dst + 3, acc.w);
    }
}

// ---------------------------------------------------------------------------
// out[OFF_ES + d*NE + k] = esT[k][d]  (coalesced transpose, 16 codes/block)
__global__ void es_out_kernel(const float* __restrict__ esT,
                              float* __restrict__ out) {
    __shared__ float t2[DIM][17];
    int k0 = blockIdx.x * 16;
    int tid = threadIdx.x;
    for (int t = 0; t < 4; ++t) {
        int i = t * 256 + tid;          // 1024 float4 units over 16x64
        int k = i >> 6, dq = i & 63;
        float4 v = ((const float4*)esT)[(size_t)(k0 + k) * 64 + dq];
        t2[dq * 4 + 0][k] = v.x;
        t2[dq * 4 + 1][k] = v.y;
        t2[dq * 4 + 2][k] = v.z;
        t2[dq * 4 + 3][k] = v.w;
    }
    __syncthreads();
    for (int t = 0; t < 16; ++t) {
        int i = t * 256 + tid;          // 4096 cells: d = i>>4, c = i&15
        int d = i >> 4, c = i & 15;
        out[OFF_ES + (size_t)d * NE + k0 + c] = t2[d][c];
    }
}

// ===========================================================================
extern "C" void kernel_launch(void* const* d_in, const int* in_sizes, int n_in,
                              void* d_out, int out_size, void* d_ws, size_t ws_size,
                              hipStream_t stream) {
    const float* x     = (const float*)d_in[0];
    const float* embed = (const float*)d_in[1];
    float* out = (float*)d_out;

    // ws layout (~47 MB)
    char* p = (char*)d_ws;
    unsigned short* Xbf  = (unsigned short*)p;  p += (size_t)NTOK * DIM * 2;    // 8.4 MB
    unsigned short* EbfT = (unsigned short*)p;  p += (size_t)NE * DIM * 2;      // 4.2 MB (tiled)
    float* embedT = (float*)p;                  p += (size_t)NE * DIM * 4;      // 8.4 MB
    float* e2     = (float*)p;                  p += (size_t)NE * 4;
    float* es2    = (float*)p;                  p += (size_t)NE * 4;
    unsigned int* cand = (unsigned int*)p;      p += (size_t)NTOK * NCAND * 4;  // 16.8 MB
    int*   ind    = (int*)p;                    p += (size_t)NTOK * 4;
    int*   start  = (int*)p;                    p += (size_t)NE * 4;
    int*   cur    = (int*)p;                    p += (size_t)NE * 4;
    int*   list   = (int*)p;                    p += (size_t)(NTOK + 16) * 4;   // +16 pad
    int*   work   = (int*)p;                    p += (size_t)16384 * 4;
    int*   nwork  = (int*)p;                    p += 64;
    float* esT    = (float*)p;                  p += (size_t)NE * DIM * 4;      // 8.4 MB

    // zero DIFF/IND/OH header (Q and ES fully overwritten) + esT accumulator
    hipMemsetAsync((char*)d_out + (size_t)OFF_DIFF * 4, 0,
                   ((size_t)(OFF_ES - OFF_DIFF)) * 4, stream);
    hipMemsetAsync(esT, 0, (size_t)NE * DIM * 4, stream);

    convert_x_kernel<<<(NTOK * DIM / 4) / 256, 256, 0, stream>>>(x, Xbf);
    convert_e_kernel<<<NE / 32, 256, 0, stream>>>(embed, EbfT, embedT, e2, es2);
    dist_screen_kernel<<<dim3(4, NTOK / 128), 256, 0, stream>>>(
        Xbf, EbfT, es2, cand);
    finalize_kernel<<<NTOK / 4, 256, 0, stream>>>(
        x, embedT, e2, cand, ind, out);
    scan_kernel<<<1, 256, 0, stream>>>(out, start, cur, work, nwork);
    scatter_kernel<<<NTOK / 256, 256, 0, stream>>>(ind, cur, list);
    sum_es_kernel<<<2304, 256, 0, stream>>>(x, start, list, work, nwork, esT);
    es_out_kernel<<<NE / 16, 256, 0, stream>>>(esT, out);
}